// Round 11
// baseline (145.175 us; speedup 1.0000x reference)
//
#include <hip/hip_runtime.h>
#include <hip/hip_bf16.h>

typedef short short8 __attribute__((ext_vector_type(8)));
typedef float f32x4 __attribute__((ext_vector_type(4)));

// Workspace byte offsets
#define WF_OFF  0u        // bf16 wfrag[t=27][ot=2][lane=64][j=8] = 55296 B
#define RWB_OFF 55296u    // f32 rw_sum[b]*bias_sum[o] : [8][32] = 1024 B
#define RWS_OFF 56320u    // f32 rw_sum[8] = 32 B

// Ring-4 LDS planes, CHUNK-MAJOR rows (R10 layout, unchanged):
// row = [chunk 0..3][col 0..23] x 16 B; chunk stride 384 (quad term drops out
// of bank index), row stride 1552 (spreads writes). Read = quad*384 + lx*16
// -> bank 4*lx mod 32: conflict-free b128 reads.
#define CHS 384
#define RB  1552
#define PLANE_B (10 * RB)      // 15520 B
#define RING_B (4 * PLANE_B)   // 62080 B  (2 blocks/CU)

// Raw barriers (T3/T4): NO vmcnt drain — __syncthreads would wait vmcnt(0)
// for in-flight output stores + prefetch loads every burst (the measured
// ~25K-cycle/burst stall). lgkmcnt(0) only where ds_writes must be visible.
#define SCHED0() __builtin_amdgcn_sched_barrier(0)
#define BAR_RAW()  do { SCHED0(); __builtin_amdgcn_s_barrier(); SCHED0(); } while (0)
#define BAR_LGKM() do { SCHED0(); asm volatile("s_waitcnt lgkmcnt(0)" ::: "memory"); \
                        __builtin_amdgcn_s_barrier(); SCHED0(); } while (0)

__device__ __forceinline__ unsigned bf16rne(float f) {
    unsigned u = __float_as_uint(f);
    return (u + 0x7FFFu + ((u >> 16) & 1u)) >> 16;
}

// ---------------------------------------------------------------------------
// Prep: wfrag in MFMA A-operand layout; rwb_bias; rw_sum. (unchanged, proven)
// ---------------------------------------------------------------------------
__global__ void condconv_prep(const float* __restrict__ rw,      // [8,8]
                              const float* __restrict__ weight,  // [8,32,32,27]
                              const float* __restrict__ bias,    // [8,32]
                              char* __restrict__ ws) {
    int i = blockIdx.x * 256 + threadIdx.x;
    if (i < 27648) {
        int t   = i >> 10;
        int rem = i & 1023;
        int ot  = rem >> 9;
        int l   = (rem >> 3) & 63;
        int j   = rem & 7;
        int o   = ot * 16 + (l & 15);
        int c   = 8 * (l >> 4) + j;
        float s = 0.f;
#pragma unroll
        for (int e = 0; e < 8; ++e) s += weight[((e * 32 + o) * 32 + c) * 27 + t];
        ((unsigned short*)(ws + WF_OFF))[i] = (unsigned short)bf16rne(s);
    } else if (i < 27904) {
        int k = i - 27648;
        int b = k >> 5, o = k & 31;
        float rs = 0.f, bs = 0.f;
#pragma unroll
        for (int e = 0; e < 8; ++e) { rs += rw[b * 8 + e]; bs += bias[e * 32 + o]; }
        ((float*)(ws + RWB_OFF))[k] = rs * bs;
        if (o == 0) ((float*)(ws + RWS_OFF))[b] = rs;
    }
}

// ---------------------------------------------------------------------------
// z-walk conv, z-step 2, ring-4, raw barriers + issue-early staging.
// Burst k: { BAR_RAW (slots free) ; SWRITE 2 planes (loads issued last burst,
// counted vmcnt by compiler) ; SLOAD next 2 planes (fire) ; BAR_LGKM ;
// 216 MFMA/wave ; output stores (never waited on) }.
// Everything else (layout, XCD swizzle, epilogue) identical to R10.
// ---------------------------------------------------------------------------
__global__ __launch_bounds__(256, 2) void condconv_zwalk4(
        const float* __restrict__ x,     // [8,32,16,64,64] fp32
        const char* __restrict__ wf,     // ws + WF_OFF
        const float* __restrict__ rwbias,
        const float* __restrict__ rwsum,
        float* __restrict__ out) {
    __shared__ __align__(16) char smem[RING_B];

    const int tid  = threadIdx.x;
    const int wv   = tid >> 6;
    const int lane = tid & 63;
    const int n    = lane & 15;
    const int quad = lane >> 4;
    const int ot   = wv & 1;
    const int yh   = wv >> 1;

    // 512 blocks, bijective XCD swizzle (512 % 8 == 0): b outermost.
    const int logical = (blockIdx.x & 7) * 64 + (blockIdx.x >> 3);
    const int b   = logical >> 6;
    const int rem = logical & 63;
    const int zb  = rem & 1;
    const int xb  = (rem >> 1) & 3;
    const int yb  = rem >> 3;
    const int y0 = yb * 8, x0 = xb * 16, zr0 = zb * 8;

    const float* xbp = x + (size_t)b * 2097152;   // 32*16*64*64

    // ---- staging map: 240 active threads = scc(4) x syp(10) x sx4(6).
    const bool sact = tid < 240;
    const int  scc  = tid / 60;                   // 0..3
    const int  rr   = tid % 60;
    const int  syp  = rr / 6;                     // 0..9
    const int  sx4  = rr % 6;                     // 0..5
    const int  gxq  = xb * 4 + sx4 - 1;           // global x-quad
    const int  gy   = y0 + syp - 1;
    const bool gok  = ((unsigned)gxq < 16u) && ((unsigned)gy < 64u);
    const long soff = (long)scc * 524288 +        // 8 c-planes per chunk
                      (long)(gok ? gy : 0) * 64 + (long)(gok ? gxq : 0) * 4;
    const int  woff = syp * RB + scc * CHS + (4 * sx4) * 16;

    // ---- hoisted weight fragments: 27 taps for this wave's o-tile.
    short8 wreg[27];
    {
        const char* wb_ = wf + lane * 16 + ot * 1024;
#pragma unroll
        for (int t = 0; t < 27; ++t) wreg[t] = *(const short8*)(wb_ + t * 2048);
    }

    // ---- epilogue constants
    const float rwb = rwsum[b];
    float bb[4];
#pragma unroll
    for (int j = 0; j < 4; ++j) bb[j] = rwbias[b * 32 + ot * 16 + quad * 4 + j];
    float* outb = out + (size_t)(b * 32 + ot * 16 + quad * 4) * 65536 +
                  (size_t)(y0 + yh * 4) * 64 + x0 + n;

    // ---- prefetch registers: 2 planes in flight (16 float4 = 64 VGPR)
    float4 pX[8], pY[8];

    auto SLOAD = [&](int p, float4 (&dst)[8]) {
        if (!sact) return;
        if (gok && (unsigned)p < 16u) {
            const float* q0 = xbp + soff + (long)p * 4096;
#pragma unroll
            for (int kk = 0; kk < 8; ++kk)
                dst[kk] = *(const float4*)(q0 + (size_t)kk * 65536);
        } else {
#pragma unroll
            for (int kk = 0; kk < 8; ++kk)
                dst[kk] = make_float4(0.f, 0.f, 0.f, 0.f);
        }
    };
    auto SWRITE = [&](int p, const float4 (&v)[8]) {
        if (!sact) return;
        char* pl = smem + (p & 3) * PLANE_B;
        float a[8][4];
#pragma unroll
        for (int kk = 0; kk < 8; ++kk) {
            a[kk][0] = v[kk].x; a[kk][1] = v[kk].y;
            a[kk][2] = v[kk].z; a[kk][3] = v[kk].w;
        }
#pragma unroll
        for (int xi = 0; xi < 4; ++xi) {
            union { __hip_bfloat162 h2[4]; uint4 u; } g;
            g.h2[0] = __float22bfloat162_rn(make_float2(a[0][xi], a[1][xi]));
            g.h2[1] = __float22bfloat162_rn(make_float2(a[2][xi], a[3][xi]));
            g.h2[2] = __float22bfloat162_rn(make_float2(a[4][xi], a[5][xi]));
            g.h2[3] = __float22bfloat162_rn(make_float2(a[6][xi], a[7][xi]));
            *(uint4*)(pl + woff + xi * 16) = g.u;
        }
    };

    // ---- prologue: planes zr0-1, zr0 -> slots 3, 0; prefetch zr0+1, zr0+2.
    SLOAD(zr0 - 1, pX);
    SLOAD(zr0, pY);
    SWRITE(zr0 - 1, pX);
    SWRITE(zr0, pY);
    SLOAD(zr0 + 1, pX);
    SLOAD(zr0 + 2, pY);

    f32x4 accA[4] = {}, accB[4] = {};

#pragma unroll 1
    for (int k = 0; k < 4; ++k) {
        const int zA = zr0 + 2 * k;

        BAR_RAW();                 // prior burst's ds_reads retired (per-wave
                                   // lgkm waits before MFMA) -> slots free
        SWRITE(zA + 1, pX);        // counted vmcnt wait (loads long in flight)
        SWRITE(zA + 2, pY);
        if (k < 3) {               // issue-early: next burst's planes; their
            SLOAD(zA + 3, pX);     // HBM round trip hides under compute below
            SLOAD(zA + 4, pY);
        }
        BAR_LGKM();                // ds_writes visible; NO vmcnt drain

#pragma unroll
        for (int pi = 0; pi < 4; ++pi) {
            const char* Pp = smem + ((zA - 1 + pi) & 3) * PLANE_B;
#pragma unroll
            for (int q = 0; q < 6; ++q) {
                const char* rowq = Pp + (yh * 4 + q) * RB + quad * CHS;
#pragma unroll
                for (int dx = 0; dx < 3; ++dx) {
                    const int lx = n + dx + 3;
                    const short8 xf = *(const short8*)(rowq + lx * 16);
#pragma unroll
                    for (int dy = 0; dy < 3; ++dy) {
                        const int r = q - dy;
                        if (r >= 0 && r < 4) {
                            if (pi < 3)
                                accA[r] = __builtin_amdgcn_mfma_f32_16x16x32_bf16(
                                    wreg[pi * 9 + dy * 3 + dx], xf, accA[r], 0, 0, 0);
                            if (pi > 0)
                                accB[r] = __builtin_amdgcn_mfma_f32_16x16x32_bf16(
                                    wreg[(pi - 1) * 9 + dy * 3 + dx], xf, accB[r], 0, 0, 0);
                        }
                    }
                }
            }
        }

        // write outputs zA (accA), zA+1 (accB); stores are never waited on
#pragma unroll
        for (int r = 0; r < 4; ++r) {
#pragma unroll
            for (int j = 0; j < 4; ++j) {
                float* po = outb + (size_t)j * 65536 + r * 64;
                po[(size_t)zA * 4096]       = rwb * accA[r][j] + bb[j];
                po[(size_t)(zA + 1) * 4096] = rwb * accB[r][j] + bb[j];
            }
            accA[r] = f32x4{0, 0, 0, 0};
            accB[r] = f32x4{0, 0, 0, 0};
        }
    }
}

// ---------------------------------------------------------------------------
extern "C" void kernel_launch(void* const* d_in, const int* in_sizes, int n_in,
                              void* d_out, int out_size, void* d_ws, size_t ws_size,
                              hipStream_t stream) {
    const float* x      = (const float*)d_in[0];  // [8,32,16,64,64]
    const float* rw     = (const float*)d_in[1];  // [8,8]
    const float* weight = (const float*)d_in[2];  // [8,32,32,27]
    const float* bias   = (const float*)d_in[3];  // [8,32]
    float* out = (float*)d_out;
    char*  ws  = (char*)d_ws;

    condconv_prep<<<109, 256, 0, stream>>>(rw, weight, bias, ws);
    // 512 blocks = 8 b x 8 y-tiles x 4 x-chunks x 2 z-halves (XCD-swizzled).
    condconv_zwalk4<<<512, 256, 0, stream>>>(
        x, ws + WF_OFF,
        (const float*)(ws + RWB_OFF), (const float*)(ws + RWS_OFF), out);
}